// Round 9
// baseline (473.801 us; speedup 1.0000x reference)
//
#include <hip/hip_runtime.h>
#include <math.h>

typedef __attribute__((ext_vector_type(8))) short bshort8;
typedef __attribute__((ext_vector_type(4))) float f32x4;

#define DI __device__ __forceinline__

DI unsigned short f2bf(float x) {
    unsigned int u = __builtin_bit_cast(unsigned int, x);
    u += 0x7fffu + ((u >> 16) & 1u);
    return (unsigned short)(u >> 16);
}

DI bshort8 pack8(const float* v) {
    bshort8 r;
    #pragma unroll
    for (int j = 0; j < 8; j++) r[j] = (short)f2bf(v[j]);
    return r;
}

DI f32x4 mfma16(bshort8 a, bshort8 b, f32x4 c) {
    return __builtin_amdgcn_mfma_f32_16x16x32_bf16(a, b, c, 0, 0, 0);
}

// ---- composite (bilinear resize N->112, align_corners=False) + 8x8 avgpool stencils ----
__device__ const float W14[14][3] = {
    {0.875f, 0.125f, 0.f},
    {0.125f, 0.75f, 0.125f}, {0.125f, 0.75f, 0.125f}, {0.125f, 0.75f, 0.125f},
    {0.125f, 0.75f, 0.125f}, {0.125f, 0.75f, 0.125f}, {0.125f, 0.75f, 0.125f},
    {0.125f, 0.75f, 0.125f}, {0.125f, 0.75f, 0.125f}, {0.125f, 0.75f, 0.125f},
    {0.125f, 0.75f, 0.125f}, {0.125f, 0.75f, 0.125f}, {0.125f, 0.75f, 0.125f},
    {0.125f, 0.875f, 0.f}};
__device__ const float W28[14][4] = {
    {0.5f, 0.4375f, 0.0625f, 0.f},
    {0.0625f, 0.4375f, 0.4375f, 0.0625f}, {0.0625f, 0.4375f, 0.4375f, 0.0625f},
    {0.0625f, 0.4375f, 0.4375f, 0.0625f}, {0.0625f, 0.4375f, 0.4375f, 0.0625f},
    {0.0625f, 0.4375f, 0.4375f, 0.0625f}, {0.0625f, 0.4375f, 0.4375f, 0.0625f},
    {0.0625f, 0.4375f, 0.4375f, 0.0625f}, {0.0625f, 0.4375f, 0.4375f, 0.0625f},
    {0.0625f, 0.4375f, 0.4375f, 0.0625f}, {0.0625f, 0.4375f, 0.4375f, 0.0625f},
    {0.0625f, 0.4375f, 0.4375f, 0.0625f}, {0.0625f, 0.4375f, 0.4375f, 0.0625f},
    {0.0625f, 0.4375f, 0.5f, 0.f}};
__device__ const float W56[14][6] = {
    {0.25f, 0.25f, 0.25f, 0.21875f, 0.03125f, 0.f},
    {0.03125f, 0.21875f, 0.25f, 0.25f, 0.21875f, 0.03125f},
    {0.03125f, 0.21875f, 0.25f, 0.25f, 0.21875f, 0.03125f},
    {0.03125f, 0.21875f, 0.25f, 0.25f, 0.21875f, 0.03125f},
    {0.03125f, 0.21875f, 0.25f, 0.25f, 0.21875f, 0.03125f},
    {0.03125f, 0.21875f, 0.25f, 0.25f, 0.21875f, 0.03125f},
    {0.03125f, 0.21875f, 0.25f, 0.25f, 0.21875f, 0.03125f},
    {0.03125f, 0.21875f, 0.25f, 0.25f, 0.21875f, 0.03125f},
    {0.03125f, 0.21875f, 0.25f, 0.25f, 0.21875f, 0.03125f},
    {0.03125f, 0.21875f, 0.25f, 0.25f, 0.21875f, 0.03125f},
    {0.03125f, 0.21875f, 0.25f, 0.25f, 0.21875f, 0.03125f},
    {0.03125f, 0.21875f, 0.25f, 0.25f, 0.21875f, 0.03125f},
    {0.03125f, 0.21875f, 0.25f, 0.25f, 0.21875f, 0.03125f},
    {0.03125f, 0.21875f, 0.25f, 0.25f, 0.25f, 0.f}};

// -------- c2 path (N=112): direct 16B vector loads, 8x8 non-overlap mean --------
DI void pool_body112(const float* __restrict__ src, unsigned short* __restrict__ dst,
                     unsigned blk, unsigned t)
{
    unsigned id = blk * 256u + t;
    unsigned p = id / 196u;
    unsigned r = id - p * 196u;
    unsigned ti = r / 14u, tj = r - ti * 14u;
    unsigned b = p >> 8, cin = p & 255u;
    const float* plane = src + (size_t)p * 12544;
    const float4* p4 = (const float4*)(plane + (size_t)(ti * 8) * 112 + tj * 8);
    float4 rv[16];
    #pragma unroll
    for (int i = 0; i < 8; i++) { rv[2 * i] = p4[i * 28]; rv[2 * i + 1] = p4[i * 28 + 1]; }
    float acc = 0.f;
    #pragma unroll
    for (int i = 0; i < 16; i++) acc += (rv[i].x + rv[i].y) + (rv[i].z + rv[i].w);
    dst[(size_t)cin * 1568 + b * 196 + r] = f2bf(acc * (1.f / 64.f));
}

// -------- K1: all pools + c5 mean + hoisted Wa; LDS-staged, batched planes --------
// grid: 1568 (c2) + 4096 (c3) + 2048 (c4 x4) + 1024 (c5 x16) + 16 (Wa) = 8752
__global__ __launch_bounds__(256) void pool_all(
    const float* __restrict__ c2, const float* __restrict__ c3,
    const float* __restrict__ c4, const float* __restrict__ c5,
    unsigned short* __restrict__ pf0, unsigned short* __restrict__ pf1,
    unsigned short* __restrict__ pf2, unsigned short* __restrict__ pf3,
    float* __restrict__ pooled,
    const float* __restrict__ gat_W, const float* __restrict__ gat_a,
    float* __restrict__ Wa)
{
    __shared__ alignas(16) float ls[3360];
    unsigned bx = blockIdx.x, t = threadIdx.x;

    if (bx < 1568u) {                       // ---- c2: N=112 direct ----
        pool_body112(c2, pf0, bx, t);
        return;
    }
    if (bx < 5664u) {                       // ---- c3: N=56, block per plane ----
        unsigned p = bx - 1568u;
        unsigned b = p >> 9, cin = p & 511u;
        const float* plane = c3 + (size_t)p * 3136;
        float4* l4 = (float4*)ls;
        const float4* s4 = (const float4*)plane;
        for (int i = t; i < 784; i += 256) l4[i] = s4[i];
        __syncthreads();
        if (t < 196) {
            int ti = t / 14, tj = t - ti * 14;
            int hs = 4 * ti - 1; if (hs < 0) hs = 0;
            int ws = 4 * tj - 1; if (ws < 0) ws = 0;
            float acc = 0.f;
            #pragma unroll
            for (int i = 0; i < 6; i++) {
                int hi = hs + i; if (hi > 55) hi = 55;
                const float* row = ls + hi * 56;
                float rs = 0.f;
                #pragma unroll
                for (int j = 0; j < 6; j++) {
                    int wj = ws + j; if (wj > 55) wj = 55;
                    rs += W56[tj][j] * row[wj];
                }
                acc += W56[ti][i] * rs;
            }
            pf1[(size_t)cin * 1568 + b * 196 + t] = f2bf(acc);
        }
        return;
    }
    if (bx < 7712u) {                       // ---- c4: N=28, FOUR planes per block ----
        unsigned g = bx - 5664u;
        unsigned p0 = g * 4;                // 4 consecutive planes, contiguous memory
        float4* l4 = (float4*)ls;
        const float4* s4 = (const float4*)(c4 + (size_t)p0 * 784);
        for (int i = t; i < 784; i += 256) l4[i] = s4[i];
        __syncthreads();
        for (int o = t; o < 784; o += 256) {
            int pl = o / 196, r = o - pl * 196;
            int ti = r / 14, tj = r - ti * 14;
            int hs = 2 * ti - 1; if (hs < 0) hs = 0;
            int ws = 2 * tj - 1; if (ws < 0) ws = 0;
            const float* base = ls + pl * 784;
            float acc = 0.f;
            #pragma unroll
            for (int i = 0; i < 4; i++) {
                int hi = hs + i; if (hi > 27) hi = 27;
                const float* row = base + hi * 28;
                float rs = 0.f;
                #pragma unroll
                for (int j = 0; j < 4; j++) {
                    int wj = ws + j; if (wj > 27) wj = 27;
                    rs += W28[tj][j] * row[wj];
                }
                acc += W28[ti][i] * rs;
            }
            unsigned p = p0 + pl;
            unsigned b = p >> 10, cin = p & 1023u;
            pf2[(size_t)cin * 1568 + b * 196 + r] = f2bf(acc);
        }
        return;
    }
    if (bx < 8736u) {                       // ---- c5: N=14, SIXTEEN planes/block (4/wave) ----
        unsigned g = bx - 7712u;
        int wid = t >> 6, lane = t & 63;
        unsigned pbase = g * 16 + wid * 4;
        float* lw = ls + wid * 840;         // 4 planes x 210 (14 rows x stride 15)
        #pragma unroll
        for (int sub = 0; sub < 4; sub++) {
            unsigned p = pbase + sub;
            const float* plane = c5 + (size_t)p * 196;
            float a0 = plane[lane];
            float a1 = plane[64 + lane];
            float a2 = plane[128 + lane];
            float a3 = (lane < 4) ? plane[192 + lane] : 0.f;
            float* lp = lw + sub * 210;
            {
                int i0 = lane,        r0 = i0 / 14, c0 = i0 - r0 * 14;
                int i1 = 64 + lane,   r1 = i1 / 14, c1 = i1 - r1 * 14;
                int i2 = 128 + lane,  r2 = i2 / 14, c2 = i2 - r2 * 14;
                lp[r0 * 15 + c0] = a0;
                lp[r1 * 15 + c1] = a1;
                lp[r2 * 15 + c2] = a2;
                if (lane < 4) {
                    int i3 = 192 + lane, r3 = i3 / 14, c3 = i3 - r3 * 14;
                    lp[r3 * 15 + c3] = a3;
                }
            }
            float v = a0 + a1 + a2 + a3;
            #pragma unroll
            for (int off = 32; off > 0; off >>= 1) v += __shfl_xor(v, off, 64);
            if (lane == 0) pooled[p] = v * (1.f / 196.f);
        }
        __syncthreads();
        #pragma unroll
        for (int sub = 0; sub < 4; sub++) {
            unsigned p = pbase + sub;
            unsigned b = p >> 11, cin = p & 2047u;
            const float* lp = lw + sub * 210;
            unsigned short* dst = pf3 + (size_t)cin * 1568 + b * 196;
            #pragma unroll
            for (int rr = 0; rr < 4; rr++) {
                int r = rr * 64 + lane;
                if (r < 196) {
                    int ti = r / 14, tj = r - ti * 14;
                    int hs = ti - 1; if (hs < 0) hs = 0;
                    int ws = tj - 1; if (ws < 0) ws = 0;
                    float acc = 0.f;
                    #pragma unroll
                    for (int i = 0; i < 3; i++) {
                        int hi = hs + i; if (hi > 13) hi = 13;
                        const float* row = lp + hi * 15;
                        float rs = 0.f;
                        #pragma unroll
                        for (int j = 0; j < 3; j++) {
                            int wj = ws + j; if (wj > 13) wj = 13;
                            rs += W14[tj][j] * row[wj];
                        }
                        acc += W14[ti][i] * rs;
                    }
                    dst[r] = f2bf(acc);
                }
            }
        }
        return;
    }
    {                                       // ---- Wa: 16 blocks, one (h,q) each ----
        unsigned e = bx - 8736u;
        int h = e >> 2, q = e & 3;
        float* a1 = ls;
        float* a2 = ls + 256;
        a1[t] = gat_a[h * 512 + t];
        a2[t] = gat_a[h * 512 + 256 + t];
        __syncthreads();
        int w = t >> 6, lane = t & 63;
        #pragma unroll
        for (int ci = 0; ci < 16; ci++) {
            int c = q * 64 + w * 16 + ci;
            const float* row = gat_W + (size_t)h * 65536 + (size_t)c * 256;
            float p1 = 0.f, p2 = 0.f;
            #pragma unroll
            for (int jj = 0; jj < 4; jj++) {
                float v = row[lane + 64 * jj];
                p1 += v * a1[lane + 64 * jj];
                p2 += v * a2[lane + 64 * jj];
            }
            #pragma unroll
            for (int off = 32; off > 0; off >>= 1) {
                p1 += __shfl_xor(p1, off, 64);
                p2 += __shfl_xor(p2, off, 64);
            }
            if (lane == 0) { Wa[h * 512 + c] = p1; Wa[h * 512 + 256 + c] = p2; }
        }
    }
}

// -------- K2a: partial GEMV for sw MLP layer 1 (split-K) --------
__global__ __launch_bounds__(512) void sw_part(
    const float* __restrict__ pooled, const float* __restrict__ sp_w1,
    float* __restrict__ partial)
{
    int t = threadIdx.x;
    int b = blockIdx.x, kc = blockIdx.y;
    __shared__ float ps[256];
    if (t < 256) ps[t] = pooled[b * 2048 + kc * 256 + t];
    __syncthreads();
    float acc = 0.f;
    const float* w = sp_w1 + (size_t)(kc * 256) * 512 + t;
    #pragma unroll 8
    for (int c = 0; c < 256; c++) acc += ps[c] * w[(size_t)c * 512];
    partial[((size_t)b * 8 + kc) * 512 + t] = acc;
}

// -------- K2b: finish sw MLP + bias-init xtok + hoisted ldot + zero xmsum --------
__global__ __launch_bounds__(512) void sw_fin(
    const float* __restrict__ partial, const float* __restrict__ sp_b1,
    const float* __restrict__ sp_w2, const float* __restrict__ sp_b2,
    const float* __restrict__ lb0, const float* __restrict__ lb1,
    const float* __restrict__ lb2, const float* __restrict__ lb3,
    const float* __restrict__ lemb, const float* __restrict__ Wa,
    float* __restrict__ sw_out, float* __restrict__ xtok,
    float* __restrict__ ldot, float* __restrict__ xmsum)
{
    int b = blockIdx.x, t = threadIdx.x;
    __shared__ float h[512];
    __shared__ float s4s[4];
    __shared__ float swl[4];
    __shared__ float bf_s[256];
    if (t < 256) xmsum[b * 256 + t] = 0.f;
    float a = sp_b1[t];
    #pragma unroll
    for (int kc = 0; kc < 8; kc++) a += partial[((size_t)b * 8 + kc) * 512 + t];
    h[t] = fmaxf(a, 0.f);
    __syncthreads();
    int wv = t >> 6, lane = t & 63;
    if (wv < 4) {
        float acc = 0.f;
        #pragma unroll
        for (int i = 0; i < 8; i++) {
            int idx = lane + 64 * i;
            acc += h[idx] * sp_w2[idx * 4 + wv];
        }
        #pragma unroll
        for (int off = 32; off > 0; off >>= 1) acc += __shfl_xor(acc, off, 64);
        if (lane == 0) s4s[wv] = acc + sp_b2[wv];
    }
    __syncthreads();
    if (t == 0) {
        float mx = fmaxf(fmaxf(s4s[0], s4s[1]), fmaxf(s4s[2], s4s[3]));
        float e0 = expf(s4s[0] - mx), e1 = expf(s4s[1] - mx);
        float e2 = expf(s4s[2] - mx), e3 = expf(s4s[3] - mx);
        float inv = 1.f / (e0 + e1 + e2 + e3);
        swl[0] = e0 * inv; swl[1] = e1 * inv; swl[2] = e2 * inv; swl[3] = e3 * inv;
        for (int o = 0; o < 4; o++) sw_out[b * 4 + o] = swl[o];
    }
    __syncthreads();
    if (t < 256)
        bf_s[t] = swl[0] * lb0[t] + swl[1] * lb1[t] + swl[2] * lb2[t] + swl[3] * lb3[t];
    // hoisted: ldot[l][pair] = dot(lemb[l], Wa[pair]); block b handles l = 10b..10b+9
    {
        int pair = t >> 6;
        #pragma unroll
        for (int r = 0; r < 10; r++) {
            int l = b * 10 + r;
            const float* le = lemb + l * 256 + lane * 4;
            const float* wa = Wa + pair * 256 + lane * 4;
            float p = le[0] * wa[0] + le[1] * wa[1] + le[2] * wa[2] + le[3] * wa[3];
            #pragma unroll
            for (int off = 32; off > 0; off >>= 1) p += __shfl_xor(p, off, 64);
            if (lane == 0) ldot[l * 8 + pair] = p;
        }
    }
    __syncthreads();
    int c = t & 255, half = t >> 8;
    float bv = bf_s[c];
    float* xb = xtok + (size_t)b * 196 * 256 + c;
    for (int r = half; r < 196; r += 2) xb[(size_t)r * 256] = bv;
}

// -------- K3: lateral projection, 8 K-slices, bf16 pf direct-load, sw in epilogue --------
__global__ __launch_bounds__(256) void lateral_slice(
    const unsigned short* __restrict__ pf0, const unsigned short* __restrict__ pf1,
    const unsigned short* __restrict__ pf2, const unsigned short* __restrict__ pf3,
    const float* __restrict__ w0, const float* __restrict__ w1,
    const float* __restrict__ w2, const float* __restrict__ w3,
    const float* __restrict__ sw, float* __restrict__ xtok)
{
    const int sArr[8]    = {0, 1, 2, 2, 3, 3, 3, 3};
    const int koffArr[8] = {0, 0, 0, 512, 0, 512, 1024, 1536};
    const int klenArr[8] = {256, 512, 512, 512, 512, 512, 512, 512};
    int sl = blockIdx.y;
    int s = sArr[sl], koff = koffArr[sl], klen = klenArr[sl];
    const unsigned short* pf = (s == 0) ? pf0 : (s == 1) ? pf1 : (s == 2) ? pf2 : pf3;
    const float* W  = (s == 0) ? w0  : (s == 1) ? w1  : (s == 2) ? w2  : w3;

    int mt = blockIdx.x % 49, nt = blockIdx.x / 49;
    int m0 = mt * 32, n0 = nt * 64;
    __shared__ alignas(16) unsigned short As[1024];
    __shared__ alignas(16) unsigned short Bs[2048];
    int t = threadIdx.x, lane = t & 63, wid = t >> 6;
    int wm = wid >> 1, wn = wid & 1;
    f32x4 acc0 = {0, 0, 0, 0}, acc1 = {0, 0, 0, 0};

    int f = t & 63;
    int mA = m0 + ((t >> 6) & 1) * 16 + (f & 15);   // t<128
    int kbA = (f >> 4) * 8;
    int nB = n0 + (t >> 6) * 16 + (f & 15);
    int kbB = (f >> 4) * 8;

    unsigned short ark[8];
    float br[8];
    auto loadA = [&](int k0) {
        if (t < 128) {
            const unsigned short* base = pf + (size_t)(koff + k0 + kbA) * 1568 + mA;
            #pragma unroll
            for (int j = 0; j < 8; j++) ark[j] = base[(size_t)j * 1568];
        }
    };
    auto loadB = [&](int k0) {
        const float* base = W + (size_t)(koff + k0 + kbB) * 256 + nB;
        #pragma unroll
        for (int j = 0; j < 8; j++) br[j] = base[(size_t)j * 256];
    };

    loadA(0); loadB(0);
    for (int k0 = 0; k0 < klen; k0 += 32) {
        if (t < 128) {
            bshort8 v8;
            #pragma unroll
            for (int j = 0; j < 8; j++) v8[j] = (short)ark[j];
            *(bshort8*)&As[(((t >> 6) & 1) * 512 + f * 8)] = v8;
        }
        *(bshort8*)&Bs[((t >> 6) * 512 + f * 8)] = pack8(br);
        __syncthreads();
        if (k0 + 32 < klen) { loadA(k0 + 32); loadB(k0 + 32); }
        bshort8 av = *(const bshort8*)&As[wm * 512 + lane * 8];
        bshort8 bv0 = *(const bshort8*)&Bs[(wn * 2 + 0) * 512 + lane * 8];
        bshort8 bv1 = *(const bshort8*)&Bs[(wn * 2 + 1) * 512 + lane * 8];
        acc0 = mfma16(av, bv0, acc0);
        acc1 = mfma16(av, bv1, acc1);
        __syncthreads();
    }
    int col0 = n0 + wn * 32 + (lane & 15);
    int rbase = m0 + wm * 16 + ((lane >> 4) << 2);
    #pragma unroll
    for (int r = 0; r < 4; r++) {
        int m = rbase + r;
        float swv = sw[(m / 196) * 4 + s];
        atomicAdd(&xtok[(size_t)m * 256 + col0], acc0[r] * swv);
        atomicAdd(&xtok[(size_t)m * 256 + col0 + 16], acc1[r] * swv);
    }
}

// -------- generic bf16-MFMA GEMM (used for qkv only) --------
template <bool B_IS_KXN>
__global__ __launch_bounds__(256) void gemm_kernel(
    const float* __restrict__ Ab, int lda, long long sAy, long long sAz,
    const float* __restrict__ Bb, int ldb, long long sBy, long long sBz,
    float* __restrict__ Cb, int ldc, long long sCy, long long sCz,
    const float* __restrict__ bias, int M, int N, int K,
    float alpha, int mtiles)
{
    const float* A = Ab + blockIdx.y * sAy + blockIdx.z * sAz;
    const float* B = Bb + blockIdx.y * sBy + blockIdx.z * sBz;
    float* C = Cb + blockIdx.y * sCy + blockIdx.z * sCz;
    int mt = blockIdx.x % mtiles, nt = blockIdx.x / mtiles;
    int m0 = mt * 32, n0 = nt * 64;
    __shared__ alignas(16) unsigned short As[1024];
    __shared__ alignas(16) unsigned short Bs[2048];
    int t = threadIdx.x, lane = t & 63, wid = t >> 6;
    int wm = wid >> 1, wn = wid & 1;
    f32x4 acc0 = {0, 0, 0, 0}, acc1 = {0, 0, 0, 0};

    int f = t & 63;
    int mA = m0 + ((t >> 6) & 1) * 16 + (f & 15);   // t<128
    int kbA = (f >> 4) * 8;
    int nB = n0 + (t >> 6) * 16 + (f & 15);
    int kbB = (f >> 4) * 8;

    float ar[8], br[8];
    auto loadA = [&](int k0) {
        if (t < 128) {
            int kb = k0 + kbA;
            if (mA < M && kb + 8 <= K) {
                const float4* p = (const float4*)(A + (size_t)mA * lda + kb);
                float4 u = p[0], v = p[1];
                ar[0] = u.x; ar[1] = u.y; ar[2] = u.z; ar[3] = u.w;
                ar[4] = v.x; ar[5] = v.y; ar[6] = v.z; ar[7] = v.w;
            } else {
                #pragma unroll
                for (int j = 0; j < 8; j++) {
                    int k = kb + j;
                    ar[j] = (mA < M && k < K) ? A[(size_t)mA * lda + k] : 0.f;
                }
            }
        }
    };
    auto loadB = [&](int k0) {
        int kb = k0 + kbB;
        if constexpr (B_IS_KXN) {
            #pragma unroll
            for (int j = 0; j < 8; j++) {
                int k = kb + j;
                br[j] = (k < K && nB < N) ? B[(size_t)k * ldb + nB] : 0.f;
            }
        } else {
            if (nB < N && kb + 8 <= K) {
                const float4* p = (const float4*)(B + (size_t)nB * ldb + kb);
                float4 u = p[0], v = p[1];
                br[0] = u.x; br[1] = u.y; br[2] = u.z; br[3] = u.w;
                br[4] = v.x; br[5] = v.y; br[6] = v.z; br[7] = v.w;
            } else {
                #pragma unroll
                for (int j = 0; j < 8; j++) {
                    int k = kb + j;
                    br[j] = (nB < N && k < K) ? B[(size_t)nB * ldb + k] : 0.f;
                }
            }
        }
    };

    loadA(0); loadB(0);
    for (int k0 = 0; k0 < K; k0 += 32) {
        if (t < 128) *(bshort8*)&As[(((t >> 6) & 1) * 512 + f * 8)] = pack8(ar);
        *(bshort8*)&Bs[((t >> 6) * 512 + f * 8)] = pack8(br);
        __syncthreads();
        if (k0 + 32 < K) { loadA(k0 + 32); loadB(k0 + 32); }
        bshort8 av = *(const bshort8*)&As[wm * 512 + lane * 8];
        bshort8 bv0 = *(const bshort8*)&Bs[(wn * 2 + 0) * 512 + lane * 8];
        bshort8 bv1 = *(const bshort8*)&Bs[(wn * 2 + 1) * 512 + lane * 8];
        acc0 = mfma16(av, bv0, acc0);
        acc1 = mfma16(av, bv1, acc1);
        __syncthreads();
    }
    int col0 = n0 + wn * 32 + (lane & 15);
    int rbase = m0 + wm * 16 + ((lane >> 4) << 2);
    #pragma unroll
    for (int r = 0; r < 4; r++) {
        int m = rbase + r;
        if (m < M) {
            if (col0 < N) {
                float v = acc0[r] * alpha;
                if (bias) v += bias[col0];
                C[(size_t)m * ldc + col0] = v;
            }
            int c1 = col0 + 16;
            if (c1 < N) {
                float v = acc1[r] * alpha;
                if (bias) v += bias[c1];
                C[(size_t)m * ldc + c1] = v;
            }
        }
    }
}

// -------- fused attention: S, softmax, PV in LDS; xm column-sum fused in epilogue --------
__global__ __launch_bounds__(256) void fused_attn(
    const float* __restrict__ qkv, float* __restrict__ xo,
    float* __restrict__ xmsum)
{
    int mt = blockIdx.x, h = blockIdx.y, b = blockIdx.z;
    const float* Qb = qkv + (size_t)b * 150528 + h * 32;
    const float* Kb = Qb + 256;
    const float* Vb = Qb + 512;

    __shared__ alignas(16) unsigned short As[1024];
    __shared__ alignas(16) unsigned short Bs[2048];
    __shared__ float Ss[32 * 256];

    int t = threadIdx.x, lane = t & 63, wid = t >> 6;
    int wm = wid >> 1, wn = wid & 1;
    int f = t & 63;
    int m0 = mt * 32;

    // ---- stage A (q tile: 32 rows x K=32) ----
    if (t < 128) {
        float ar[8];
        int mA = m0 + ((t >> 6) & 1) * 16 + (f & 15);
        int kb = (f >> 4) * 8;
        if (mA < 196) {
            const float4* p = (const float4*)(Qb + (size_t)mA * 768 + kb);
            float4 u = p[0], v = p[1];
            ar[0] = u.x; ar[1] = u.y; ar[2] = u.z; ar[3] = u.w;
            ar[4] = v.x; ar[5] = v.y; ar[6] = v.z; ar[7] = v.w;
        } else {
            #pragma unroll
            for (int j = 0; j < 8; j++) ar[j] = 0.f;
        }
        *(bshort8*)&As[(((t >> 6) & 1) * 512 + f * 8)] = pack8(ar);
    }

    // ---- S phase: 4 groups of 64 keys ----
    {
        int nBl = (t >> 6) * 16 + (f & 15);
        int kbB = (f >> 4) * 8;
        float br[8];
        auto loadB = [&](int g) {
            int key = g * 64 + nBl;
            if (key < 196) {
                const float4* p = (const float4*)(Kb + (size_t)key * 768 + kbB);
                float4 u = p[0], v = p[1];
                br[0] = u.x; br[1] = u.y; br[2] = u.z; br[3] = u.w;
                br[4] = v.x; br[5] = v.y; br[6] = v.z; br[7] = v.w;
            } else {
                #pragma unroll
                for (int j = 0; j < 8; j++) br[j] = 0.f;
            }
        };
        loadB(0);
        for (int g = 0; g < 4; g++) {
            __syncthreads();                              // Bs reuse guard
            *(bshort8*)&Bs[((t >> 6) * 512 + f * 8)] = pack8(br);
            __syncthreads();
            if (g < 3) loadB(g + 1);
            f32x4 acc0 = {0, 0, 0, 0}, acc1 = {0, 0, 0, 0};
            bshort8 av = *(const bshort8*)&As[wm * 512 + lane * 8];
            bshort8 bv0 = *(const bshort8*)&Bs[(wn * 2 + 0) * 512 + lane * 8];
            bshort8 bv1 = *(const bshort8*)&Bs[(wn * 2 + 1) * 512 + lane * 8];
            acc0 = mfma16(av, bv0, acc0);
            acc1 = mfma16(av, bv1, acc1);
            int col0 = g * 64 + wn * 32 + (lane & 15);
            int rbase = wm * 16 + ((lane >> 4) << 2);
            #pragma unroll
            for (int r = 0; r < 4; r++) {
                Ss[(rbase + r) * 256 + col0]      = acc0[r] * 0.17677669529663687f;
                Ss[(rbase + r) * 256 + col0 + 16] = acc1[r] * 0.17677669529663687f;
            }
        }
    }
    __syncthreads();

    // ---- softmax rows (cols 0..195); zero pad cols 196..255 ----
    {
        #pragma unroll
        for (int i = 0; i < 8; i++) {
            float* p = Ss + (wid * 8 + i) * 256;
            float v0 = p[lane], v1 = p[64 + lane], v2 = p[128 + lane];
            float v3 = (lane < 4) ? p[192 + lane] : -1e30f;
            float mx = fmaxf(fmaxf(v0, v1), fmaxf(v2, v3));
            #pragma unroll
            for (int off = 32; off > 0; off >>= 1) mx = fmaxf(mx, __shfl_xor(mx, off, 64));
            float e0 = expf(v0 - mx), e1 = expf(v1 - mx), e2 = expf(v2 - mx);
            float e3 = (lane < 4) ? expf(v3 - mx) : 0.f;
            float sum = e0 + e1 + e2 + e3;
            #pragma unroll
            for (int off = 32; off > 0; off >>= 1) sum += __shfl_xor(sum, off, 64);
            float inv = 1.f / sum;
            p[lane] = e0 * inv;
            p[64 + lane] = e1 * inv;
            p[128 + lane] = e2 * inv;
            if (lane < 4) p[192 + lane] = e3 * inv;
            else          p[192 + lane] = 0.f;            // pad cols 196..255
        }
    }
    __syncthreads();

    // ---- PV: out[32,32] = P[32,256] @ V[256(pad),32] ----
    {
        f32x4 acc0 = {0, 0, 0, 0}, acc1 = {0, 0, 0, 0};
        int nBl = (t >> 6) * 16 + (f & 15);               // 0..63, valid <32
        int kbB = (f >> 4) * 8;
        int mAl = ((t >> 6) & 1) * 16 + (f & 15);
        int kbA = (f >> 4) * 8;
        float ar[8], br[8];
        auto loadA = [&](int k0) {
            if (t < 128) {
                #pragma unroll
                for (int j = 0; j < 8; j++) ar[j] = Ss[mAl * 256 + k0 + kbA + j];
            }
        };
        auto loadB = [&](int k0) {
            #pragma unroll
            for (int j = 0; j < 8; j++) {
                int k = k0 + kbB + j;
                br[j] = (k < 196 && nBl < 32) ? Vb[(size_t)k * 768 + nBl] : 0.f;
            }
        };
        loadA(0); loadB(0);
        for (int k0 = 0; k0 < 256; k0 += 32) {
            __syncthreads();                              // As/Bs reuse guard
            if (t < 128) *(bshort8*)&As[(((t >> 6) & 1) * 512 + f * 8)] = pack8(ar);
            *(bshort8*)&Bs[((t >> 6) * 512 + f * 8)] = pack8(br);
            __syncthreads();
            if (k0 + 32 < 256) { loadA(k0 + 32); loadB(k0 + 32); }
            bshort8 av = *(const bshort8*)&As[wm * 512 + lane * 8];
            bshort8 bv0 = *(const bshort8*)&Bs[(wn * 2 + 0) * 512 + lane * 8];
            bshort8 bv1 = *(const bshort8*)&Bs[(wn * 2 + 1) * 512 + lane * 8];
            acc0 = mfma16(av, bv0, acc0);
            acc1 = mfma16(av, bv1, acc1);
        }
        int col0 = wn * 32 + (lane & 15);
        int rbase = wm * 16 + ((lane >> 4) << 2);
        if (col0 < 32) {
            float s0 = 0.f, s1 = 0.f;
            #pragma unroll
            for (int r = 0; r < 4; r++) {
                int m = m0 + rbase + r;
                if (m < 196) {
                    xo[((size_t)b * 196 + m) * 256 + h * 32 + col0]      = acc0[r];
                    xo[((size_t)b * 196 + m) * 256 + h * 32 + col0 + 16] = acc1[r];
                    s0 += acc0[r];
                    s1 += acc1[r];
                }
            }
            // token-mean partials (column sums); zeroed by sw_fin
            atomicAdd(&xmsum[b * 256 + h * 32 + col0], s0);
            atomicAdd(&xmsum[b * 256 + h * 32 + col0 + 16], s1);
        }
    }
}

// ================= tail, stage 1: one block per (b,h) — 32 blocks =================
__global__ __launch_bounds__(1024) void tail1(
    const float* __restrict__ xmsum, const float* __restrict__ proj_w,
    const float* __restrict__ proj_b,
    const float* __restrict__ gat_W, const float* __restrict__ lemb,
    const float* __restrict__ Wa, const float* __restrict__ ldot,
    float* __restrict__ atts, float* __restrict__ hm_g)
{
    int b = blockIdx.x >> 2, h = blockIdx.x & 3;
    int t = threadIdx.x, lane = t & 63, wv = t >> 6;
    __shared__ float red[1024];
    __shared__ float xm[256];
    __shared__ float gctx_s[256];
    __shared__ float gdot_s[2];
    __shared__ float s12h[160];
    __shared__ float am_s[80];
    __shared__ float av_s[256];

    if (t < 256) xm[t] = xmsum[b * 256 + t] * (1.f / 196.f);
    if (t < 80) am_s[t] = 0.f;
    __syncthreads();

    {
        int n = t & 255, ks = t >> 8;
        float acc = 0.f;
        const float* w = proj_w + (size_t)(ks * 64) * 256 + n;
        #pragma unroll 8
        for (int i = 0; i < 64; i++) acc += xm[ks * 64 + i] * w[(size_t)i * 256];
        red[t] = acc;
    }
    __syncthreads();
    if (t < 256) gctx_s[t] = proj_b[t] + red[t] + red[256 + t] + red[512 + t] + red[768 + t];
    __syncthreads();

    if (wv < 2) {
        int pair = h * 2 + wv;
        const float* wa = Wa + pair * 256 + lane * 4;
        float p = gctx_s[lane * 4] * wa[0] + gctx_s[lane * 4 + 1] * wa[1]
                + gctx_s[lane * 4 + 2] * wa[2] + gctx_s[lane * 4 + 3] * wa[3];
        #pragma unroll
        for (int off = 32; off > 0; off >>= 1) p += __shfl_xor(p, off, 64);
        if (lane == 0) gdot_s[wv] = p;
    }
    __syncthreads();
    if (t < 160) {
        int q = t / 80, l = t - q * 80;
        s12h[t] = ldot[l * 8 + h * 2 + q] + gdot_s[q];
    }
    __syncthreads();

    {
        #pragma unroll
        for (int rr = 0; rr < 5; rr++) {
            int i = rr * 16 + wv;
            float s1i = s12h[i];
            const float* s2 = s12h + 80;
            float v0 = s1i + s2[lane]; v0 = v0 > 0.f ? v0 : 0.2f * v0;
            float v1 = -1e30f;
            if (lane < 16) { v1 = s1i + s2[64 + lane]; v1 = v1 > 0.f ? v1 : 0.2f * v1; }
            float mx = fmaxf(v0, v1);
            #pragma unroll
            for (int off = 32; off > 0; off >>= 1) mx = fmaxf(mx, __shfl_xor(mx, off, 64));
            float e0 = expf(v0 - mx), e1 = (lane < 16) ? expf(v1 - mx) : 0.f;
            float sum = e0 + e1;
            #pragma unroll
            for (int off = 32; off > 0; off >>= 1) sum += __shfl_xor(sum, off, 64);
            float inv = 1.f / sum;
            float* orow = atts + (size_t)h * 51200 + b * 6400 + i * 80;
            float p0 = e0 * inv;
            orow[lane] = p0;
            atomicAdd(&am_s[lane], p0);
            if (lane < 16) {
                float p1 = e1 * inv;
                orow[64 + lane] = p1;
                atomicAdd(&am_s[64 + lane], p1);
            }
        }
    }
    __syncthreads();

    {
        int n = t & 255, ks = t >> 8;
        float acc = 0.f;
        const float* le = lemb + n;
        #pragma unroll 5
        for (int l = ks * 20; l < ks * 20 + 20; l++) acc += am_s[l] * le[(size_t)l * 256];
        red[t] = acc;
    }
    __syncthreads();
    if (t < 256)
        av_s[t] = (red[t] + red[256 + t] + red[512 + t] + red[768 + t]) * (1.f / 80.f)
                + gctx_s[t];
    __syncthreads();
    {
        int n = t & 255, ks = t >> 8;
        float acc = 0.f;
        const float* w = gat_W + (size_t)h * 65536 + (size_t)(ks * 64) * 256 + n;
        #pragma unroll 8
        for (int i = 0; i < 64; i++) acc += av_s[ks * 64 + i] * w[(size_t)i * 256];
        red[t] = acc;
    }
    __syncthreads();
    if (t < 256)
        hm_g[(b * 4 + h) * 256 + t] = red[t] + red[256 + t] + red[512 + t] + red[768 + t];
}

// ================= tail, stage 2: one block per b — 8 blocks =================
__global__ __launch_bounds__(1024) void tail2(
    const float* __restrict__ hm_g,
    const float* __restrict__ out_w, const float* __restrict__ out_b,
    const float* __restrict__ spec_w1, const float* __restrict__ spec_b1,
    const float* __restrict__ spec_w2, const float* __restrict__ spec_b2,
    const float* __restrict__ spat_w1, const float* __restrict__ spat_b1,
    const float* __restrict__ spat_w2, const float* __restrict__ spat_b2,
    const float* __restrict__ gate_w, const float* __restrict__ gate_b,
    const float* __restrict__ unc_w, const float* __restrict__ unc_b,
    float* __restrict__ out)
{
    int b = blockIdx.x, t = threadIdx.x;
    __shared__ float red[1024];
    __shared__ float as_s[256];
    __shared__ float hb_s[256];
    __shared__ float fv_s[320];

    {
        int n = t & 255, ks = t >> 8;
        float acc = 0.f;
        const float* hv = hm_g + b * 1024 + ks * 256;
        const float* w = out_w + (size_t)(ks * 256) * 256 + n;
        #pragma unroll 8
        for (int k = 0; k < 256; k++) acc += hv[k] * w[(size_t)k * 256];
        red[t] = acc;
    }
    __syncthreads();
    if (t < 256) as_s[t] = out_b[t] + red[t] + red[256 + t] + red[512 + t] + red[768 + t];
    __syncthreads();

    {
        int u = t & 255, ks = t >> 8;
        int which = u >> 7, oo = u & 127;
        const float* w1 = which ? spat_w1 : spec_w1;
        float acc = 0.f;
        #pragma unroll 8
        for (int i = 0; i < 64; i++) {
            int k = ks * 64 + i;
            acc += as_s[k] * w1[(size_t)k * 128 + oo];
        }
        red[t] = acc;
    }
    __syncthreads();
    if (t < 256) {
        int which = t >> 7, oo = t & 127;
        const float* b1 = which ? spat_b1 : spec_b1;
        hb_s[t] = fmaxf(red[t] + red[256 + t] + red[512 + t] + red[768 + t] + b1[oo], 0.f);
    }
    __syncthreads();

    if (t < 960) {
        int sub = t / 320, u = t - sub * 320;
        int head = u / 80, o = u - head * 80;
        const float* wp; const float* src; int K;
        if (head == 0)      { wp = spec_w2; src = hb_s;       K = 128; }
        else if (head == 1) { wp = spat_w2; src = hb_s + 128; K = 128; }
        else if (head == 2) { wp = gate_w;  src = as_s;       K = 256; }
        else                { wp = unc_w;   src = as_s;       K = 256; }
        int k0 = (K * sub) / 3, k1 = (K * (sub + 1)) / 3;
        float acc = 0.f;
        for (int k = k0; k < k1; k++) acc += src[k] * wp[(size_t)k * 80 + o];
        red[sub * 320 + u] = acc;
    }
    __syncthreads();
    if (t < 320) {
        int head = t / 80, o = t - head * 80;
        const float* bp = head == 0 ? spec_b2 : head == 1 ? spat_b2 : head == 2 ? gate_b : unc_b;
        fv_s[t] = red[t] + red[320 + t] + red[640 + t] + bp[o];
    }
    __syncthreads();

    if (t < 80) {
        float sp = fv_s[t], st2 = fv_s[80 + t], gz = fv_s[160 + t], uz = fv_s[240 + t];
        float g = 1.f / (1.f + expf(-gz));
        out[b * 80 + t] = g * sp + (1.f - g) * st2;
        out[640 + b * 80 + t] = sp;
        out[1280 + b * 80 + t] = st2;
        out[1920 + b * 80 + t] = g;
        red[t] = log1pf(expf(uz)) + 1.f;
    }
    __syncthreads();
    if (t == 0) {
        float s = 0.f;
        for (int l = 0; l < 80; l++) s += red[l];
        out[2560 + b] = 80.f / s;
    }
}

// ---------------- launcher ----------------
extern "C" void kernel_launch(void* const* d_in, const int* in_sizes, int n_in,
                              void* d_out, int out_size, void* d_ws, size_t ws_size,
                              hipStream_t stream)
{
    (void)in_sizes; (void)n_in; (void)out_size; (void)ws_size;
    const float* c2 = (const float*)d_in[0];
    const float* c3 = (const float*)d_in[1];
    const float* c4 = (const float*)d_in[2];
    const float* c5 = (const float*)d_in[3];
    const float* lat_w0 = (const float*)d_in[4];
    const float* lat_b0 = (const float*)d_in[5];
    const float* lat_w1 = (const float*)d_in[6];
    const float* lat_b1 = (const float*)d_in[7];
    const float* lat_w2 = (const float*)d_in[8];
    const float* lat_b2 = (const float*)d_in[9];
    const float* lat_w3 = (const float*)d_in[10];
    const float* lat_b3 = (const float*)d_in[11];
    const float* sp_w1 = (const float*)d_in[12];
    const float* sp_b1 = (const float*)d_in[13];
    const float* sp_w2 = (const float*)d_in[14];
    const float* sp_b2 = (const float*)d_in[15];
    const float* qkv_w = (const float*)d_in[16];
    const float* qkv_b = (const float*)d_in[17];
    const float* proj_w = (const float*)d_in[18];
    const float* proj_b = (const float*)d_in[19];
    const float* gat_W = (const float*)d_in[20];
    const float* gat_a = (const float*)d_in[21];
    const float* out_w = (const float*)d_in[22];
    const float* out_b = (const float*)d_in[23];
    const float* label_emb = (const float*)d_in[24];
    const float* spec_w1 = (const float*)d_in[25];
    const float* spec_b1 = (const float*)d_in[26];
    const float* spec_w2 = (const float*)d_in[27];
    const float* spec_b2 = (const float*)d_in[28];
    const float* spat_w1 = (const float*)d_in[29];
    const float* spat_b1 = (const float*)d_in[30];
    const float* spat_w2 = (const float*)d_in[31];
    const float* spat_b2 = (const float*)d_in[32];
    const float* gate_w = (const float*)d_in[33];
    const float* gate_b = (const float*)d_in[34];
    const float* unc_w = (const float*)d_in[35];
    const float* unc_b = (const float*)d_in[36];

    float* out = (float*)d_out;
    float* ws = (float*)d_ws;

    // workspace layout (floats); pf buffers bf16 (ushort) in same regions
    unsigned short* pf0 = (unsigned short*)(ws + 0);        // 401408 elems
    unsigned short* pf1 = (unsigned short*)(ws + 401408);   // 802816
    unsigned short* pf2 = (unsigned short*)(ws + 1204224);  // 1605632
    unsigned short* pf3 = (unsigned short*)(ws + 2809856);  // 3211264 (ends 6021120)
    float* pooled = ws + 6021120;  // 16384  -> 6037504
    float* swpart = ws + 6039552;  // 32768  -> 6072320
    float* Wa     = ws + 6072320;  // 2048   -> 6074368
    float* ldot   = ws + 6074368;  // 640    -> 6075008
    float* xmsum  = ws + 6075008;  // 2048   -> 6077056
    float* qkv    = ws + 0;        // reuses pf0/pf1 region (dead after lateral)
    float* xo     = ws + 3662848;  // 401408 -> 4064256
    float* hm_g   = ws + 4253696;  // 8192   -> 4261888
    float* xtok   = ws + 6106112;  // 401408 -> 6507520

    float* swp  = out + 2568;  // sw [8,4] (output 5)
    float* atts = out + 2600;  // atts [4,8,80,80] (output 6)

    // 1. ALL pools (batched planes, padded LDS) + c5 mean + hoisted Wa
    pool_all<<<8752, 256, 0, stream>>>(c2, c3, c4, c5, pf0, pf1, pf2, pf3, pooled,
                                       gat_W, gat_a, Wa);
    // 2. scale-weight MLP partials
    sw_part<<<dim3(8, 8), 512, 0, stream>>>(pooled, sp_w1, swpart);
    // 2b. finish sw MLP + bias-init xtok + hoisted ldot + zero xmsum
    sw_fin<<<8, 512, 0, stream>>>(swpart, sp_b1, sp_w2, sp_b2,
                                  lat_b0, lat_b1, lat_b2, lat_b3,
                                  label_emb, Wa, swp, xtok, ldot, xmsum);
    // 3. lateral projection (bf16 pf direct-load, sw in epilogue) -> xtok [1568,256]
    lateral_slice<<<dim3(196, 8), 256, 0, stream>>>(pf0, pf1, pf2, pf3,
                                                    lat_w0, lat_w1, lat_w2, lat_w3,
                                                    swp, xtok);
    // 4. qkv = x @ qkv_w + qkv_b : [1568,768]
    gemm_kernel<true><<<dim3(49 * 12, 1, 1), 256, 0, stream>>>(
        xtok, 256, 0, 0, qkv_w, 768, 0, 0, qkv, 768, 0, 0,
        qkv_b, 1568, 768, 256, 1.f, 49);
    // 5. fused attention (S, softmax, PV) -> xo; accumulates xmsum column sums
    fused_attn<<<dim3(7, 8, 8), 256, 0, stream>>>(qkv, xo, xmsum);
    // 6. tail stage 1: per (b,h) — gctx/s12/softmax/av/hm (32 blocks)
    tail1<<<32, 1024, 0, stream>>>(xmsum, proj_w, proj_b, gat_W, label_emb,
                                   Wa, ldot, atts, hm_g);
    // 7. tail stage 2: per b — a_s/MLPs/heads/combine (8 blocks)
    tail2<<<8, 1024, 0, stream>>>(hm_g, out_w, out_b,
                                  spec_w1, spec_b1, spec_w2, spec_b2,
                                  spat_w1, spat_b1, spat_w2, spat_b2,
                                  gate_w, gate_b, unc_w, unc_b, out);
}